// Round 7
// baseline (374.346 us; speedup 1.0000x reference)
//
#include <hip/hip_runtime.h>
#include <hip/hip_bf16.h>

#define HW 4096
#define CCH 512
#define SDIM 64
#define BDIM 8
#define KPAD 72

typedef __attribute__((ext_vector_type(8))) short short8;
typedef __attribute__((ext_vector_type(4))) float f32x4;

static __device__ __forceinline__ ushort f2bf(float f) {
  __hip_bfloat16 h = __float2bfloat16(f);  // RNE
  return *reinterpret_cast<ushort*>(&h);
}
static __device__ __forceinline__ float bf2f(ushort u) {
  union { unsigned int u32; float f; } c;
  c.u32 = ((unsigned int)u) << 16;
  return c.f;
}

// K0: split the three projection weights into bf16 hi/mid/lo triples [br][s][c]
__global__ __launch_bounds__(256) void prep_kernel(const float* __restrict__ Wq,
                                                   const float* __restrict__ Wk,
                                                   const float* __restrict__ Wv,
                                                   ushort* __restrict__ whi,
                                                   ushort* __restrict__ wmid,
                                                   ushort* __restrict__ wlo) {
  const float* W = blockIdx.y == 0 ? Wq : (blockIdx.y == 1 ? Wk : Wv);
  const int idx = blockIdx.x * 1024 + threadIdx.x * 4;
  float4 f = *reinterpret_cast<const float4*>(&W[idx]);
  ushort4 h, m, l;
  float r, r2;
  h.x = f2bf(f.x); r = f.x - bf2f(h.x); m.x = f2bf(r); r2 = r - bf2f(m.x); l.x = f2bf(r2);
  h.y = f2bf(f.y); r = f.y - bf2f(h.y); m.y = f2bf(r); r2 = r - bf2f(m.y); l.y = f2bf(r2);
  h.z = f2bf(f.z); r = f.z - bf2f(h.z); m.z = f2bf(r); r2 = r - bf2f(m.z); l.z = f2bf(r2);
  h.w = f2bf(f.w); r = f.w - bf2f(h.w); m.w = f2bf(r); r2 = r - bf2f(m.w); l.w = f2bf(r2);
  const size_t o = (size_t)blockIdx.y * (SDIM * CCH) + idx;
  *reinterpret_cast<ushort4*>(&whi[o])  = h;
  *reinterpret_cast<ushort4*>(&wmid[o]) = m;
  *reinterpret_cast<ushort4*>(&wlo[o])  = l;
}

// K1: 3-way-split bf16 MFMA projection, Ootomo-style two accumulators.
//   M-tile = 64 (LDS 27.6 KB -> 5 blocks/CU for latency hiding)
//   ap[br][hw][b][s] = sum_c x_br[b][c][hw] * w_br[s][c]
__global__ __launch_bounds__(256) void proj_mfma_kernel(const float* __restrict__ q,
                                                        const float* __restrict__ k,
                                                        const float* __restrict__ v,
                                                        const ushort* __restrict__ whi,
                                                        const ushort* __restrict__ wmid,
                                                        const ushort* __restrict__ wlo,
                                                        float* __restrict__ ap) {
  __shared__ ushort Xh[64 * KPAD];
  __shared__ ushort Xm[64 * KPAD];
  __shared__ ushort Xl[64 * KPAD];
  const int mt = blockIdx.x;   // hw tile of 64
  const int b = blockIdx.y;
  const int br = blockIdx.z;
  const float* x = br == 0 ? q : (br == 1 ? k : v);
  const ushort* wh = whi + (size_t)br * SDIM * CCH;
  const ushort* wm = wmid + (size_t)br * SDIM * CCH;
  const ushort* wl = wlo + (size_t)br * SDIM * CCH;
  float* apo = ap + (size_t)br * HW * 512;
  const int hw0 = mt * 64;
  const int tid = threadIdx.x;
  const int l = tid & 63;
  const int wstrip = (tid >> 6) * 16;  // wave's 16-row m-strip
  const int row16 = l & 15;
  const int kgrp = l >> 4;
  const int mstage = tid & 63;         // staging: one m row per thread
  const int kq = tid >> 6;             // staging: which 16-c quarter

  f32x4 acc_hi[4] = {};
  f32x4 acc_co[4] = {};

  for (int c0 = 0; c0 < CCH; c0 += 64) {
    __syncthreads();
    // stage A tile [64 m][64 k] as hi/mid/lo bf16, transposed from x's [k][m] layout
    float xv[16];
    const float* xp = x + ((size_t)b * CCH + c0 + kq * 16) * HW + hw0 + mstage;
#pragma unroll
    for (int i = 0; i < 16; ++i) xv[i] = xp[(size_t)i * HW];
    ushort* dh = &Xh[mstage * KPAD + kq * 16];
    ushort* dm = &Xm[mstage * KPAD + kq * 16];
    ushort* dl = &Xl[mstage * KPAD + kq * 16];
#pragma unroll
    for (int j = 0; j < 2; ++j) {
      ushort th[8], tm[8], tl[8];
#pragma unroll
      for (int i = 0; i < 8; ++i) {
        float f = xv[j * 8 + i];
        ushort h = f2bf(f);
        float r = f - bf2f(h);
        ushort mm = f2bf(r);
        float r2 = r - bf2f(mm);
        th[i] = h; tm[i] = mm; tl[i] = f2bf(r2);
      }
      *reinterpret_cast<short8*>(&dh[j * 8]) = *reinterpret_cast<const short8*>(th);
      *reinterpret_cast<short8*>(&dm[j * 8]) = *reinterpret_cast<const short8*>(tm);
      *reinterpret_cast<short8*>(&dl[j * 8]) = *reinterpret_cast<const short8*>(tl);
    }
    __syncthreads();
#pragma unroll
    for (int ks = 0; ks < 2; ++ks) {
      short8 ah, am, al, bh[4], bm[4], bl[4];
      {
        const int off = (wstrip + row16) * KPAD + ks * 32 + kgrp * 8;
        ah = *reinterpret_cast<const short8*>(&Xh[off]);
        am = *reinterpret_cast<const short8*>(&Xm[off]);
        al = *reinterpret_cast<const short8*>(&Xl[off]);
      }
#pragma unroll
      for (int nf = 0; nf < 4; ++nf) {
        const size_t off = (size_t)(nf * 16 + row16) * CCH + c0 + ks * 32 + kgrp * 8;
        bh[nf] = *reinterpret_cast<const short8*>(&wh[off]);
        bm[nf] = *reinterpret_cast<const short8*>(&wm[off]);
        bl[nf] = *reinterpret_cast<const short8*>(&wl[off]);
      }
#pragma unroll
      for (int nf = 0; nf < 4; ++nf) {
        // dominant term -> its own accumulator (rounds at full scale once/term)
        acc_hi[nf] = __builtin_amdgcn_mfma_f32_16x16x32_bf16(ah, bh[nf], acc_hi[nf], 0, 0, 0);
        // correction terms -> separate accumulator (round at 2^-9 scale)
        acc_co[nf] = __builtin_amdgcn_mfma_f32_16x16x32_bf16(ah, bm[nf], acc_co[nf], 0, 0, 0);
        acc_co[nf] = __builtin_amdgcn_mfma_f32_16x16x32_bf16(am, bh[nf], acc_co[nf], 0, 0, 0);
        acc_co[nf] = __builtin_amdgcn_mfma_f32_16x16x32_bf16(am, bm[nf], acc_co[nf], 0, 0, 0);
        acc_co[nf] = __builtin_amdgcn_mfma_f32_16x16x32_bf16(ah, bl[nf], acc_co[nf], 0, 0, 0);
        acc_co[nf] = __builtin_amdgcn_mfma_f32_16x16x32_bf16(al, bh[nf], acc_co[nf], 0, 0, 0);
        acc_co[nf] = __builtin_amdgcn_mfma_f32_16x16x32_bf16(am, bl[nf], acc_co[nf], 0, 0, 0);
        acc_co[nf] = __builtin_amdgcn_mfma_f32_16x16x32_bf16(al, bm[nf], acc_co[nf], 0, 0, 0);
      }
    }
  }
#pragma unroll
  for (int nf = 0; nf < 4; ++nf)
#pragma unroll
    for (int r = 0; r < 4; ++r) {
      const int m = hw0 + wstrip + kgrp * 4 + r;
      apo[(size_t)m * 512 + b * 64 + nf * 16 + row16] = acc_hi[nf][r] + acc_co[nf][r];
    }
}

// K2: rD[br][h][s][t] = 1 / sum_w exp( sum_b A[h,w,b,s]*B[h,w,b,t] )
__global__ __launch_bounds__(512) void denom_kernel(const float* __restrict__ ap,
                                                    float* __restrict__ rD) {
  __shared__ float As[8 * 64];
  __shared__ float Bs[8 * 64];
  const int h = blockIdx.x, br = blockIdx.y;
  const float* A  = ap + ((size_t)br * HW + (size_t)h * 64) * (BDIM * SDIM);
  const float* Bp = ap + ((size_t)((br + 1) % 3) * HW + (size_t)h * 64) * (BDIM * SDIM);
  const int tid = threadIdx.x;
  const int t = tid & 63;
  const int sb = (tid >> 6) * 8;
  float D[8] = {};
  for (int w = 0; w < 64; ++w) {
    __syncthreads();
    As[tid] = A[w * (BDIM * SDIM) + tid];
    Bs[tid] = Bp[w * (BDIM * SDIM) + tid];
    __syncthreads();
    float bv[8];
#pragma unroll
    for (int b = 0; b < 8; ++b) bv[b] = Bs[b * 64 + t];
#pragma unroll
    for (int j = 0; j < 8; ++j) {
      float m = 0.f;
#pragma unroll
      for (int b = 0; b < 8; ++b) m = fmaf(As[b * 64 + sb + j], bv[b], m);
      D[j] += __expf(m);
    }
  }
#pragma unroll
  for (int j = 0; j < 8; ++j)
    rD[((size_t)(br * 64 + h) * 64 + sb + j) * 64 + t] = 1.0f / D[j];
}

// K3: on[br][hw][b][s] = o[s][b]/N[b], o = mtilde * C^T
__global__ __launch_bounds__(256) void attn_kernel(const float* __restrict__ ap,
                                                   const float* __restrict__ rD,
                                                   float* __restrict__ on) {
  __shared__ float As[8 * 64], Bs[8 * 64], Cs[8 * 64];
  __shared__ float Ms[64 * 68];  // [s][t] padded
  const int wc = blockIdx.x, h = blockIdx.y, br = blockIdx.z;
  const float* A  = ap + ((size_t)br * HW + h * 64) * 512;
  const float* Bp = ap + ((size_t)((br + 1) % 3) * HW + h * 64) * 512;
  const float* Cp = ap + ((size_t)((br + 2) % 3) * HW + h * 64) * 512;
  const float* rDp = rD + (size_t)(br * 64 + h) * 4096;  // [s][t]
  const int tid = threadIdx.x;
  for (int w = wc * 8; w < wc * 8 + 8; ++w) {
    __syncthreads();
#pragma unroll
    for (int it = 0; it < 2; ++it) {
      int idx = it * 256 + tid;
      As[idx] = A[w * 512 + idx];
      Bs[idx] = Bp[w * 512 + idx];
      Cs[idx] = Cp[w * 512 + idx];
    }
    __syncthreads();
    {
      const int t = tid & 63, sg = tid >> 6;
      float bv[8];
#pragma unroll
      for (int b = 0; b < 8; ++b) bv[b] = Bs[b * 64 + t];
#pragma unroll
      for (int j = 0; j < 16; ++j) {
        int s = sg * 16 + j;
        float m = 0.f;
#pragma unroll
        for (int b = 0; b < 8; ++b) m = fmaf(As[b * 64 + s], bv[b], m);
        Ms[s * 68 + t] = __expf(m) * rDp[s * 64 + t];
      }
    }
    __syncthreads();
    const int s2 = tid & 63, bq = tid >> 6;
    float o0 = 0.f, o1 = 0.f;
#pragma unroll
    for (int tt = 0; tt < 64; tt += 4) {
      float4 mv = *reinterpret_cast<const float4*>(&Ms[s2 * 68 + tt]);
      float4 c0 = *reinterpret_cast<const float4*>(&Cs[bq * 64 + tt]);
      float4 c1 = *reinterpret_cast<const float4*>(&Cs[(bq + 4) * 64 + tt]);
      o0 = fmaf(mv.w, c0.w, fmaf(mv.z, c0.z, fmaf(mv.y, c0.y, fmaf(mv.x, c0.x, o0))));
      o1 = fmaf(mv.w, c1.w, fmaf(mv.z, c1.z, fmaf(mv.y, c1.y, fmaf(mv.x, c1.x, o1))));
    }
    float n0 = o0, n1 = o1;
#pragma unroll
    for (int off = 32; off > 0; off >>= 1) {
      n0 += __shfl_xor(n0, off);
      n1 += __shfl_xor(n1, off);
    }
    const float r0 = 1.0f / n0, r1 = 1.0f / n1;
    const size_t ob = ((size_t)br * HW + h * 64 + w) * 512;
    on[ob + (size_t)bq * 64 + s2] = o0 * r0;
    on[ob + (size_t)(bq + 4) * 64 + s2] = o1 * r1;
  }
}

// K4: out[brb][c][hw] = sum_s on[br][hw][b][s] * wl[c][s]
__global__ __launch_bounds__(256) void out_kernel(const float* __restrict__ on,
                                                  const float* __restrict__ wl,
                                                  float* __restrict__ out) {
  __shared__ float Ol[64 * 68];  // [hw][s] padded
  const int c0 = blockIdx.x * 64;
  const int hw0 = blockIdx.y * 64;
  const int brb = blockIdx.z;
  const int br = brb >> 3, b = brb & 7;
  const int tid = threadIdx.x;
  const int lane = tid & 63;
  const int cq = __builtin_amdgcn_readfirstlane(tid >> 6);
#pragma unroll
  for (int it = 0; it < 4; ++it) {
    int f = (it * 256 + tid) * 4;
    int i = f >> 6, s = f & 63;
    *reinterpret_cast<float4*>(&Ol[i * 68 + s]) =
        *reinterpret_cast<const float4*>(&on[((size_t)(br * HW + hw0 + i) * 8 + b) * 64 + s]);
  }
  __syncthreads();
  float4 orow[16];
#pragma unroll
  for (int qd = 0; qd < 16; ++qd)
    orow[qd] = *reinterpret_cast<const float4*>(&Ol[lane * 68 + qd * 4]);
  float acc[16];
#pragma unroll
  for (int j = 0; j < 16; ++j) {
    const float* wrow = &wl[(size_t)(c0 + cq * 16 + j) * 64];
    float a = 0.f;
#pragma unroll
    for (int qd = 0; qd < 16; ++qd) {
      float4 wv = *reinterpret_cast<const float4*>(&wrow[qd * 4]);
      a = fmaf(orow[qd].w, wv.w, fmaf(orow[qd].z, wv.z, fmaf(orow[qd].y, wv.y, fmaf(orow[qd].x, wv.x, a))));
    }
    acc[j] = a;
  }
#pragma unroll
  for (int j = 0; j < 16; ++j)
    out[((size_t)brb * 512 + c0 + cq * 16 + j) * HW + hw0 + lane] = acc[j];
}

extern "C" void kernel_launch(void* const* d_in, const int* in_sizes, int n_in,
                              void* d_out, int out_size, void* d_ws, size_t ws_size,
                              hipStream_t stream) {
  const float* q  = (const float*)d_in[0];
  const float* k  = (const float*)d_in[1];
  const float* v  = (const float*)d_in[2];
  const float* Wq = (const float*)d_in[3];
  const float* Wk = (const float*)d_in[4];
  const float* Wv = (const float*)d_in[5];
  const float* Wl = (const float*)d_in[6];
  float* out = (float*)d_out;

  float* ap = (float*)d_ws;                         // 3*HW*B*S floats = 25.2 MB
  float* rD = ap + (size_t)3 * HW * 512;            // 3*64*64*64 floats = 3.1 MB
  float* on = rD + (size_t)3 * 64 * 64 * 64;        // 3*HW*B*S floats = 25.2 MB
  ushort* whi  = (ushort*)rD;                       // 3*64*512*2B = 192 KB, consumed before denom
  ushort* wmid = whi + (size_t)3 * SDIM * CCH;
  ushort* wlo  = wmid + (size_t)3 * SDIM * CCH;

  prep_kernel<<<dim3(32, 3), 256, 0, stream>>>(Wq, Wk, Wv, whi, wmid, wlo);
  proj_mfma_kernel<<<dim3(64, 8, 3), 256, 0, stream>>>(q, k, v, whi, wmid, wlo, ap);
  denom_kernel<<<dim3(64, 3), 512, 0, stream>>>(ap, rD);
  attn_kernel<<<dim3(8, 64, 3), 256, 0, stream>>>(ap, rD, on);
  out_kernel<<<dim3(8, 64, 24), 256, 0, stream>>>(on, Wl, out);
}

// Round 8
// 352.255 us; speedup vs baseline: 1.0627x; 1.0627x over previous
//
#include <hip/hip_runtime.h>
#include <hip/hip_bf16.h>

#define HW 4096
#define CCH 512
#define SDIM 64
#define BDIM 8
#define XSTRIDE 130   // f32 row stride for staged x tile (2k+row banks -> 2-way, free)

typedef __attribute__((ext_vector_type(8))) short short8;
typedef __attribute__((ext_vector_type(4))) float f32x4;

static __device__ __forceinline__ ushort f2bf(float f) {
  __hip_bfloat16 h = __float2bfloat16(f);  // RNE
  return *reinterpret_cast<ushort*>(&h);
}
static __device__ __forceinline__ float bf2f(ushort u) {
  union { unsigned int u32; float f; } c;
  c.u32 = ((unsigned int)u) << 16;
  return c.f;
}

// K0: split the three projection weights into bf16 hi/mid/lo triples [br][s][c]
__global__ __launch_bounds__(256) void prep_kernel(const float* __restrict__ Wq,
                                                   const float* __restrict__ Wk,
                                                   const float* __restrict__ Wv,
                                                   ushort* __restrict__ whi,
                                                   ushort* __restrict__ wmid,
                                                   ushort* __restrict__ wlo) {
  const float* W = blockIdx.y == 0 ? Wq : (blockIdx.y == 1 ? Wk : Wv);
  const int idx = blockIdx.x * 1024 + threadIdx.x * 4;
  float4 f = *reinterpret_cast<const float4*>(&W[idx]);
  ushort4 h, m, l;
  float r, r2;
  h.x = f2bf(f.x); r = f.x - bf2f(h.x); m.x = f2bf(r); r2 = r - bf2f(m.x); l.x = f2bf(r2);
  h.y = f2bf(f.y); r = f.y - bf2f(h.y); m.y = f2bf(r); r2 = r - bf2f(m.y); l.y = f2bf(r2);
  h.z = f2bf(f.z); r = f.z - bf2f(h.z); m.z = f2bf(r); r2 = r - bf2f(m.z); l.z = f2bf(r2);
  h.w = f2bf(f.w); r = f.w - bf2f(h.w); m.w = f2bf(r); r2 = r - bf2f(m.w); l.w = f2bf(r2);
  const size_t o = (size_t)blockIdx.y * (SDIM * CCH) + idx;
  *reinterpret_cast<ushort4*>(&whi[o])  = h;
  *reinterpret_cast<ushort4*>(&wmid[o]) = m;
  *reinterpret_cast<ushort4*>(&wlo[o])  = l;
}

// K1: 3-way-split bf16 MFMA projection, Ootomo two-accumulator, M=128.
//   Staging: x tile kept f32 [64c][128hw] in LDS (pure copy, no transpose VALU);
//   split to hi/mid/lo happens in registers at fragment build (bit-identical math).
//   ap[br][hw][b][s] = sum_c x_br[b][c][hw] * w_br[s][c]
__global__ __launch_bounds__(256) void proj_mfma_kernel(const float* __restrict__ q,
                                                        const float* __restrict__ k,
                                                        const float* __restrict__ v,
                                                        const ushort* __restrict__ whi,
                                                        const ushort* __restrict__ wmid,
                                                        const ushort* __restrict__ wlo,
                                                        float* __restrict__ ap) {
  __shared__ float Xs[64 * XSTRIDE];   // 33.3 KB
  const int mt = blockIdx.x;   // hw tile of 128
  const int b = blockIdx.y;
  const int br = blockIdx.z;
  const float* x = br == 0 ? q : (br == 1 ? k : v);
  const ushort* wh = whi + (size_t)br * SDIM * CCH;
  const ushort* wm = wmid + (size_t)br * SDIM * CCH;
  const ushort* wl = wlo + (size_t)br * SDIM * CCH;
  float* apo = ap + (size_t)br * HW * 512;
  const int hw0 = mt * 128;
  const int tid = threadIdx.x;
  const int l = tid & 63;
  const int wstrip = (tid >> 6) * 32;  // wave's 32-row m-strip
  const int row16 = l & 15;
  const int kgrp = l >> 4;

  f32x4 acc_hi[2][4] = {};
  f32x4 acc_co[2][4] = {};

  for (int c0 = 0; c0 < CCH; c0 += 64) {
    __syncthreads();
    // stage [64 c][128 hw] f32: wave w, instr it covers c-row (it*4 + w), hw = 2*lane..
#pragma unroll
    for (int it = 0; it < 16; ++it) {
      const int fidx = (it * 256 + tid) * 2;
      const int cc = fidx >> 7;
      const int hwi = fidx & 127;
      *reinterpret_cast<float2*>(&Xs[cc * XSTRIDE + hwi]) =
          *reinterpret_cast<const float2*>(&x[(size_t)(b * CCH + c0 + cc) * HW + hw0 + hwi]);
    }
    __syncthreads();
#pragma unroll
    for (int ks = 0; ks < 2; ++ks) {
      short8 bh[4], bm[4], bl[4];
#pragma unroll
      for (int nf = 0; nf < 4; ++nf) {
        const size_t off = (size_t)(nf * 16 + row16) * CCH + c0 + ks * 32 + kgrp * 8;
        bh[nf] = *reinterpret_cast<const short8*>(&wh[off]);
        bm[nf] = *reinterpret_cast<const short8*>(&wm[off]);
        bl[nf] = *reinterpret_cast<const short8*>(&wl[off]);
      }
#pragma unroll
      for (int mf = 0; mf < 2; ++mf) {
        const int rowA = wstrip + mf * 16 + row16;
        short8 ah, am, al;
        {
          ushort th[8], tm[8], tl[8];
#pragma unroll
          for (int i = 0; i < 8; ++i) {
            const float f = Xs[(ks * 32 + kgrp * 8 + i) * XSTRIDE + rowA];
            const ushort h = f2bf(f);
            const float r = f - bf2f(h);
            const ushort mmv = f2bf(r);
            const float r2 = r - bf2f(mmv);
            th[i] = h; tm[i] = mmv; tl[i] = f2bf(r2);
          }
          ah = *reinterpret_cast<const short8*>(th);
          am = *reinterpret_cast<const short8*>(tm);
          al = *reinterpret_cast<const short8*>(tl);
        }
#pragma unroll
        for (int nf = 0; nf < 4; ++nf) {
          // dominant term -> own accumulator
          acc_hi[mf][nf] = __builtin_amdgcn_mfma_f32_16x16x32_bf16(ah, bh[nf], acc_hi[mf][nf], 0, 0, 0);
          // correction terms -> separate accumulator (round at 2^-9 scale)
          acc_co[mf][nf] = __builtin_amdgcn_mfma_f32_16x16x32_bf16(ah, bm[nf], acc_co[mf][nf], 0, 0, 0);
          acc_co[mf][nf] = __builtin_amdgcn_mfma_f32_16x16x32_bf16(am, bh[nf], acc_co[mf][nf], 0, 0, 0);
          acc_co[mf][nf] = __builtin_amdgcn_mfma_f32_16x16x32_bf16(am, bm[nf], acc_co[mf][nf], 0, 0, 0);
          acc_co[mf][nf] = __builtin_amdgcn_mfma_f32_16x16x32_bf16(ah, bl[nf], acc_co[mf][nf], 0, 0, 0);
          acc_co[mf][nf] = __builtin_amdgcn_mfma_f32_16x16x32_bf16(al, bh[nf], acc_co[mf][nf], 0, 0, 0);
          acc_co[mf][nf] = __builtin_amdgcn_mfma_f32_16x16x32_bf16(am, bl[nf], acc_co[mf][nf], 0, 0, 0);
          acc_co[mf][nf] = __builtin_amdgcn_mfma_f32_16x16x32_bf16(al, bm[nf], acc_co[mf][nf], 0, 0, 0);
        }
      }
    }
  }
#pragma unroll
  for (int mf = 0; mf < 2; ++mf)
#pragma unroll
    for (int nf = 0; nf < 4; ++nf)
#pragma unroll
      for (int r = 0; r < 4; ++r) {
        const int m = hw0 + wstrip + mf * 16 + kgrp * 4 + r;
        apo[(size_t)m * 512 + b * 64 + nf * 16 + row16] = acc_hi[mf][nf][r] + acc_co[mf][nf][r];
      }
}

// K2: rD[br][h][s][t] = 1 / sum_w exp( sum_b A[h,w,b,s]*B[h,w,b,t] )
//   regrid: (64 h, 8 s-groups, 3 br) = 1536 blocks of 512 threads
__global__ __launch_bounds__(512) void denom_kernel(const float* __restrict__ ap,
                                                    float* __restrict__ rD) {
  __shared__ float As[8 * 8];    // [b][sj] for this s-group
  __shared__ float Bs[8 * 64];   // [b][t]
  const int h = blockIdx.x, sg = blockIdx.y, br = blockIdx.z;
  const float* A  = ap + ((size_t)br * HW + (size_t)h * 64) * (BDIM * SDIM);
  const float* Bp = ap + ((size_t)((br + 1) % 3) * HW + (size_t)h * 64) * (BDIM * SDIM);
  const int tid = threadIdx.x;
  const int t = tid & 63;
  const int sj = tid >> 6;
  float D = 0.f;
  for (int w = 0; w < 64; ++w) {
    __syncthreads();
    if (tid < 64) As[tid] = A[w * 512 + (tid >> 3) * 64 + sg * 8 + (tid & 7)];  // [b][sj]
    Bs[tid] = Bp[w * 512 + tid];                                                // [b][t]
    __syncthreads();
    float m = 0.f;
#pragma unroll
    for (int b = 0; b < 8; ++b) m = fmaf(As[b * 8 + sj], Bs[b * 64 + t], m);
    D += __expf(m);
  }
  rD[((size_t)(br * 64 + h) * 64 + sg * 8 + sj) * 64 + t] = 1.0f / D;
}

// K3: on[br][hw][b][s] = o[s][b]/N[b], o = mtilde * C^T
__global__ __launch_bounds__(256) void attn_kernel(const float* __restrict__ ap,
                                                   const float* __restrict__ rD,
                                                   float* __restrict__ on) {
  __shared__ float As[8 * 64], Bs[8 * 64], Cs[8 * 64];
  __shared__ float Ms[64 * 68];  // [s][t] padded
  const int wc = blockIdx.x, h = blockIdx.y, br = blockIdx.z;
  const float* A  = ap + ((size_t)br * HW + h * 64) * 512;
  const float* Bp = ap + ((size_t)((br + 1) % 3) * HW + h * 64) * 512;
  const float* Cp = ap + ((size_t)((br + 2) % 3) * HW + h * 64) * 512;
  const float* rDp = rD + (size_t)(br * 64 + h) * 4096;  // [s][t]
  const int tid = threadIdx.x;
  for (int w = wc * 8; w < wc * 8 + 8; ++w) {
    __syncthreads();
#pragma unroll
    for (int it = 0; it < 2; ++it) {
      int idx = it * 256 + tid;
      As[idx] = A[w * 512 + idx];
      Bs[idx] = Bp[w * 512 + idx];
      Cs[idx] = Cp[w * 512 + idx];
    }
    __syncthreads();
    {
      const int t = tid & 63, sg = tid >> 6;
      float bv[8];
#pragma unroll
      for (int b = 0; b < 8; ++b) bv[b] = Bs[b * 64 + t];
#pragma unroll
      for (int j = 0; j < 16; ++j) {
        int s = sg * 16 + j;
        float m = 0.f;
#pragma unroll
        for (int b = 0; b < 8; ++b) m = fmaf(As[b * 64 + s], bv[b], m);
        Ms[s * 68 + t] = __expf(m) * rDp[s * 64 + t];
      }
    }
    __syncthreads();
    const int s2 = tid & 63, bq = tid >> 6;
    float o0 = 0.f, o1 = 0.f;
#pragma unroll
    for (int tt = 0; tt < 64; tt += 4) {
      float4 mv = *reinterpret_cast<const float4*>(&Ms[s2 * 68 + tt]);
      float4 c0 = *reinterpret_cast<const float4*>(&Cs[bq * 64 + tt]);
      float4 c1 = *reinterpret_cast<const float4*>(&Cs[(bq + 4) * 64 + tt]);
      o0 = fmaf(mv.w, c0.w, fmaf(mv.z, c0.z, fmaf(mv.y, c0.y, fmaf(mv.x, c0.x, o0))));
      o1 = fmaf(mv.w, c1.w, fmaf(mv.z, c1.z, fmaf(mv.y, c1.y, fmaf(mv.x, c1.x, o1))));
    }
    float n0 = o0, n1 = o1;
#pragma unroll
    for (int off = 32; off > 0; off >>= 1) {
      n0 += __shfl_xor(n0, off);
      n1 += __shfl_xor(n1, off);
    }
    const float r0 = 1.0f / n0, r1 = 1.0f / n1;
    const size_t ob = ((size_t)br * HW + h * 64 + w) * 512;
    on[ob + (size_t)bq * 64 + s2] = o0 * r0;
    on[ob + (size_t)(bq + 4) * 64 + s2] = o1 * r1;
  }
}

// K4: out[brb][c][hw] = sum_s on[br][hw][b][s] * wl[c][s]
__global__ __launch_bounds__(256) void out_kernel(const float* __restrict__ on,
                                                  const float* __restrict__ wl,
                                                  float* __restrict__ out) {
  __shared__ float Ol[64 * 68];  // [hw][s] padded
  const int c0 = blockIdx.x * 64;
  const int hw0 = blockIdx.y * 64;
  const int brb = blockIdx.z;
  const int br = brb >> 3, b = brb & 7;
  const int tid = threadIdx.x;
  const int lane = tid & 63;
  const int cq = __builtin_amdgcn_readfirstlane(tid >> 6);
#pragma unroll
  for (int it = 0; it < 4; ++it) {
    int f = (it * 256 + tid) * 4;
    int i = f >> 6, s = f & 63;
    *reinterpret_cast<float4*>(&Ol[i * 68 + s]) =
        *reinterpret_cast<const float4*>(&on[((size_t)(br * HW + hw0 + i) * 8 + b) * 64 + s]);
  }
  __syncthreads();
  float4 orow[16];
#pragma unroll
  for (int qd = 0; qd < 16; ++qd)
    orow[qd] = *reinterpret_cast<const float4*>(&Ol[lane * 68 + qd * 4]);
  float acc[16];
#pragma unroll
  for (int j = 0; j < 16; ++j) {
    const float* wrow = &wl[(size_t)(c0 + cq * 16 + j) * 64];
    float a = 0.f;
#pragma unroll
    for (int qd = 0; qd < 16; ++qd) {
      float4 wv = *reinterpret_cast<const float4*>(&wrow[qd * 4]);
      a = fmaf(orow[qd].w, wv.w, fmaf(orow[qd].z, wv.z, fmaf(orow[qd].y, wv.y, fmaf(orow[qd].x, wv.x, a))));
    }
    acc[j] = a;
  }
#pragma unroll
  for (int j = 0; j < 16; ++j)
    out[((size_t)brb * 512 + c0 + cq * 16 + j) * HW + hw0 + lane] = acc[j];
}

extern "C" void kernel_launch(void* const* d_in, const int* in_sizes, int n_in,
                              void* d_out, int out_size, void* d_ws, size_t ws_size,
                              hipStream_t stream) {
  const float* q  = (const float*)d_in[0];
  const float* k  = (const float*)d_in[1];
  const float* v  = (const float*)d_in[2];
  const float* Wq = (const float*)d_in[3];
  const float* Wk = (const float*)d_in[4];
  const float* Wv = (const float*)d_in[5];
  const float* Wl = (const float*)d_in[6];
  float* out = (float*)d_out;

  float* ap = (float*)d_ws;                         // 3*HW*B*S floats = 25.2 MB
  float* rD = ap + (size_t)3 * HW * 512;            // 3*64*64*64 floats = 3.1 MB
  float* on = rD + (size_t)3 * 64 * 64 * 64;        // 3*HW*B*S floats = 25.2 MB
  ushort* whi  = (ushort*)rD;                       // 192 KB, consumed before denom overwrites rD
  ushort* wmid = whi + (size_t)3 * SDIM * CCH;
  ushort* wlo  = wmid + (size_t)3 * SDIM * CCH;

  prep_kernel<<<dim3(32, 3), 256, 0, stream>>>(Wq, Wk, Wv, whi, wmid, wlo);
  proj_mfma_kernel<<<dim3(32, 8, 3), 256, 0, stream>>>(q, k, v, whi, wmid, wlo, ap);
  denom_kernel<<<dim3(64, 8, 3), 512, 0, stream>>>(ap, rD);
  attn_kernel<<<dim3(8, 64, 3), 256, 0, stream>>>(ap, rD, on);
  out_kernel<<<dim3(8, 64, 24), 256, 0, stream>>>(on, Wl, out);
}

// Round 9
// 328.444 us; speedup vs baseline: 1.1398x; 1.0725x over previous
//
#include <hip/hip_runtime.h>
#include <hip/hip_bf16.h>

#define HW 4096
#define CCH 512
#define SDIM 64
#define BDIM 8

typedef __attribute__((ext_vector_type(8))) short short8;
typedef __attribute__((ext_vector_type(4))) float f32x4;

static __device__ __forceinline__ ushort f2bf(float f) {
  __hip_bfloat16 h = __float2bfloat16(f);  // RNE
  return *reinterpret_cast<ushort*>(&h);
}
static __device__ __forceinline__ float bf2f(ushort u) {
  union { unsigned int u32; float f; } c;
  c.u32 = ((unsigned int)u) << 16;
  return c.f;
}

// K0: split the three projection weights into bf16 hi/mid/lo triples [br][s][c]
__global__ __launch_bounds__(256) void prep_kernel(const float* __restrict__ Wq,
                                                   const float* __restrict__ Wk,
                                                   const float* __restrict__ Wv,
                                                   ushort* __restrict__ whi,
                                                   ushort* __restrict__ wmid,
                                                   ushort* __restrict__ wlo) {
  const float* W = blockIdx.y == 0 ? Wq : (blockIdx.y == 1 ? Wk : Wv);
  const int idx = blockIdx.x * 1024 + threadIdx.x * 4;
  float4 f = *reinterpret_cast<const float4*>(&W[idx]);
  ushort4 h, m, l;
  float r, r2;
  h.x = f2bf(f.x); r = f.x - bf2f(h.x); m.x = f2bf(r); r2 = r - bf2f(m.x); l.x = f2bf(r2);
  h.y = f2bf(f.y); r = f.y - bf2f(h.y); m.y = f2bf(r); r2 = r - bf2f(m.y); l.y = f2bf(r2);
  h.z = f2bf(f.z); r = f.z - bf2f(h.z); m.z = f2bf(r); r2 = r - bf2f(m.z); l.z = f2bf(r2);
  h.w = f2bf(f.w); r = f.w - bf2f(h.w); m.w = f2bf(r); r2 = r - bf2f(m.w); l.w = f2bf(r2);
  const size_t o = (size_t)blockIdx.y * (SDIM * CCH) + idx;
  *reinterpret_cast<ushort4*>(&whi[o])  = h;
  *reinterpret_cast<ushort4*>(&wmid[o]) = m;
  *reinterpret_cast<ushort4*>(&wlo[o])  = l;
}

// K1: 3-way-split bf16 MFMA projection, Ootomo two-accumulator, M=128.
//   NO LDS: fragments loaded straight from global (64B-coalesced per 16-lane
//   group), split in registers, 2-deep register double-buffer hides HBM latency.
//   ap[br][hw][b][s] = sum_c x_br[b][c][hw] * w_br[s][c]
__global__ __launch_bounds__(256, 2) void proj_mfma_kernel(const float* __restrict__ q,
                                                           const float* __restrict__ k,
                                                           const float* __restrict__ v,
                                                           const ushort* __restrict__ whi,
                                                           const ushort* __restrict__ wmid,
                                                           const ushort* __restrict__ wlo,
                                                           float* __restrict__ ap) {
  const int mt = blockIdx.x;   // hw tile of 128
  const int b = blockIdx.y;
  const int br = blockIdx.z;
  const float* x = br == 0 ? q : (br == 1 ? k : v);
  const ushort* wh = whi + (size_t)br * SDIM * CCH;
  const ushort* wm = wmid + (size_t)br * SDIM * CCH;
  const ushort* wl = wlo + (size_t)br * SDIM * CCH;
  float* apo = ap + (size_t)br * HW * 512;
  const int hw0 = mt * 128;
  const int tid = threadIdx.x;
  const int l = tid & 63;
  const int wstrip = (tid >> 6) * 32;  // wave's 32-row m-strip
  const int row16 = l & 15;
  const int kgrp = l >> 4;
  // lane's fragment base: x[(b*CCH + c)*HW + hw0 + wstrip + mf*16 + row16]
  const float* xb = x + (size_t)b * CCH * HW + hw0 + wstrip + row16;

  f32x4 acc_hi[2][4] = {};
  f32x4 acc_co[2][4] = {};
  float buf0[2][2][8], buf1[2][2][8];

#define LOADX(BUF, C0)                                                          \
  do {                                                                          \
    _Pragma("unroll") for (int ks = 0; ks < 2; ++ks)                            \
    _Pragma("unroll") for (int mf = 0; mf < 2; ++mf)                            \
    _Pragma("unroll") for (int i = 0; i < 8; ++i)                               \
      BUF[ks][mf][i] =                                                          \
          xb[(size_t)((C0) + ks * 32 + kgrp * 8 + i) * HW + mf * 16];           \
  } while (0)

#define COMPUTE(BUF, C0)                                                                           \
  do {                                                                                             \
    _Pragma("unroll") for (int ks = 0; ks < 2; ++ks) {                                             \
      short8 bh[4], bm[4], bl[4];                                                                  \
      _Pragma("unroll") for (int nf = 0; nf < 4; ++nf) {                                           \
        const size_t off = (size_t)(nf * 16 + row16) * CCH + (C0) + ks * 32 + kgrp * 8;            \
        bh[nf] = *reinterpret_cast<const short8*>(&wh[off]);                                       \
        bm[nf] = *reinterpret_cast<const short8*>(&wm[off]);                                       \
        bl[nf] = *reinterpret_cast<const short8*>(&wl[off]);                                       \
      }                                                                                            \
      _Pragma("unroll") for (int mf = 0; mf < 2; ++mf) {                                           \
        ushort th[8], tm[8], tl[8];                                                                \
        _Pragma("unroll") for (int i = 0; i < 8; ++i) {                                            \
          const float f = BUF[ks][mf][i];                                                          \
          const ushort h = f2bf(f);                                                                \
          const float r = f - bf2f(h);                                                             \
          const ushort mv = f2bf(r);                                                               \
          const float r2 = r - bf2f(mv);                                                           \
          th[i] = h; tm[i] = mv; tl[i] = f2bf(r2);                                                 \
        }                                                                                          \
        const short8 ah = *reinterpret_cast<const short8*>(th);                                    \
        const short8 am = *reinterpret_cast<const short8*>(tm);                                    \
        const short8 al = *reinterpret_cast<const short8*>(tl);                                    \
        _Pragma("unroll") for (int nf = 0; nf < 4; ++nf) {                                         \
          acc_hi[mf][nf] = __builtin_amdgcn_mfma_f32_16x16x32_bf16(ah, bh[nf], acc_hi[mf][nf], 0, 0, 0); \
          acc_co[mf][nf] = __builtin_amdgcn_mfma_f32_16x16x32_bf16(ah, bm[nf], acc_co[mf][nf], 0, 0, 0); \
          acc_co[mf][nf] = __builtin_amdgcn_mfma_f32_16x16x32_bf16(am, bh[nf], acc_co[mf][nf], 0, 0, 0); \
          acc_co[mf][nf] = __builtin_amdgcn_mfma_f32_16x16x32_bf16(am, bm[nf], acc_co[mf][nf], 0, 0, 0); \
          acc_co[mf][nf] = __builtin_amdgcn_mfma_f32_16x16x32_bf16(ah, bl[nf], acc_co[mf][nf], 0, 0, 0); \
          acc_co[mf][nf] = __builtin_amdgcn_mfma_f32_16x16x32_bf16(al, bh[nf], acc_co[mf][nf], 0, 0, 0); \
          acc_co[mf][nf] = __builtin_amdgcn_mfma_f32_16x16x32_bf16(am, bl[nf], acc_co[mf][nf], 0, 0, 0); \
          acc_co[mf][nf] = __builtin_amdgcn_mfma_f32_16x16x32_bf16(al, bm[nf], acc_co[mf][nf], 0, 0, 0); \
        }                                                                                          \
      }                                                                                            \
    }                                                                                              \
  } while (0)

  LOADX(buf0, 0);
#pragma unroll
  for (int cc = 0; cc < 4; ++cc) {
    LOADX(buf1, cc * 128 + 64);
    COMPUTE(buf0, cc * 128);
    if (cc < 3) LOADX(buf0, cc * 128 + 128);
    COMPUTE(buf1, cc * 128 + 64);
  }
#undef LOADX
#undef COMPUTE

#pragma unroll
  for (int mf = 0; mf < 2; ++mf)
#pragma unroll
    for (int nf = 0; nf < 4; ++nf)
#pragma unroll
      for (int r = 0; r < 4; ++r) {
        const int m = hw0 + wstrip + mf * 16 + kgrp * 4 + r;
        apo[(size_t)m * 512 + b * 64 + nf * 16 + row16] = acc_hi[mf][nf][r] + acc_co[mf][nf][r];
      }
}

// K2: rD[br][h][s][t] = 1 / sum_w exp( sum_b A[h,w,b,s]*B[h,w,b,t] )
__global__ __launch_bounds__(512) void denom_kernel(const float* __restrict__ ap,
                                                    float* __restrict__ rD) {
  __shared__ float As[8 * 64];
  __shared__ float Bs[8 * 64];
  const int h = blockIdx.x, br = blockIdx.y;
  const float* A  = ap + ((size_t)br * HW + (size_t)h * 64) * (BDIM * SDIM);
  const float* Bp = ap + ((size_t)((br + 1) % 3) * HW + (size_t)h * 64) * (BDIM * SDIM);
  const int tid = threadIdx.x;
  const int t = tid & 63;
  const int sb = (tid >> 6) * 8;
  float D[8] = {};
  for (int w = 0; w < 64; ++w) {
    __syncthreads();
    As[tid] = A[w * (BDIM * SDIM) + tid];
    Bs[tid] = Bp[w * (BDIM * SDIM) + tid];
    __syncthreads();
    float bv[8];
#pragma unroll
    for (int b = 0; b < 8; ++b) bv[b] = Bs[b * 64 + t];
#pragma unroll
    for (int j = 0; j < 8; ++j) {
      float m = 0.f;
#pragma unroll
      for (int b = 0; b < 8; ++b) m = fmaf(As[b * 64 + sb + j], bv[b], m);
      D[j] += __expf(m);
    }
  }
#pragma unroll
  for (int j = 0; j < 8; ++j)
    rD[((size_t)(br * 64 + h) * 64 + sb + j) * 64 + t] = 1.0f / D[j];
}

// K3: on[br][hw][b][s] = o[s][b]/N[b], o = mtilde * C^T
__global__ __launch_bounds__(256) void attn_kernel(const float* __restrict__ ap,
                                                   const float* __restrict__ rD,
                                                   float* __restrict__ on) {
  __shared__ float As[8 * 64], Bs[8 * 64], Cs[8 * 64];
  __shared__ float Ms[64 * 68];  // [s][t] padded
  const int wc = blockIdx.x, h = blockIdx.y, br = blockIdx.z;
  const float* A  = ap + ((size_t)br * HW + h * 64) * 512;
  const float* Bp = ap + ((size_t)((br + 1) % 3) * HW + h * 64) * 512;
  const float* Cp = ap + ((size_t)((br + 2) % 3) * HW + h * 64) * 512;
  const float* rDp = rD + (size_t)(br * 64 + h) * 4096;  // [s][t]
  const int tid = threadIdx.x;
  for (int w = wc * 8; w < wc * 8 + 8; ++w) {
    __syncthreads();
#pragma unroll
    for (int it = 0; it < 2; ++it) {
      int idx = it * 256 + tid;
      As[idx] = A[w * 512 + idx];
      Bs[idx] = Bp[w * 512 + idx];
      Cs[idx] = Cp[w * 512 + idx];
    }
    __syncthreads();
    {
      const int t = tid & 63, sg = tid >> 6;
      float bv[8];
#pragma unroll
      for (int b = 0; b < 8; ++b) bv[b] = Bs[b * 64 + t];
#pragma unroll
      for (int j = 0; j < 16; ++j) {
        int s = sg * 16 + j;
        float m = 0.f;
#pragma unroll
        for (int b = 0; b < 8; ++b) m = fmaf(As[b * 64 + s], bv[b], m);
        Ms[s * 68 + t] = __expf(m) * rDp[s * 64 + t];
      }
    }
    __syncthreads();
    const int s2 = tid & 63, bq = tid >> 6;
    float o0 = 0.f, o1 = 0.f;
#pragma unroll
    for (int tt = 0; tt < 64; tt += 4) {
      float4 mv = *reinterpret_cast<const float4*>(&Ms[s2 * 68 + tt]);
      float4 c0 = *reinterpret_cast<const float4*>(&Cs[bq * 64 + tt]);
      float4 c1 = *reinterpret_cast<const float4*>(&Cs[(bq + 4) * 64 + tt]);
      o0 = fmaf(mv.w, c0.w, fmaf(mv.z, c0.z, fmaf(mv.y, c0.y, fmaf(mv.x, c0.x, o0))));
      o1 = fmaf(mv.w, c1.w, fmaf(mv.z, c1.z, fmaf(mv.y, c1.y, fmaf(mv.x, c1.x, o1))));
    }
    float n0 = o0, n1 = o1;
#pragma unroll
    for (int off = 32; off > 0; off >>= 1) {
      n0 += __shfl_xor(n0, off);
      n1 += __shfl_xor(n1, off);
    }
    const float r0 = 1.0f / n0, r1 = 1.0f / n1;
    const size_t ob = ((size_t)br * HW + h * 64 + w) * 512;
    on[ob + (size_t)bq * 64 + s2] = o0 * r0;
    on[ob + (size_t)(bq + 4) * 64 + s2] = o1 * r1;
  }
}

// K4: out[brb][c][hw] = sum_s on[br][hw][b][s] * wl[c][s]
__global__ __launch_bounds__(256) void out_kernel(const float* __restrict__ on,
                                                  const float* __restrict__ wl,
                                                  float* __restrict__ out) {
  __shared__ float Ol[64 * 68];  // [hw][s] padded
  const int c0 = blockIdx.x * 64;
  const int hw0 = blockIdx.y * 64;
  const int brb = blockIdx.z;
  const int br = brb >> 3, b = brb & 7;
  const int tid = threadIdx.x;
  const int lane = tid & 63;
  const int cq = __builtin_amdgcn_readfirstlane(tid >> 6);
#pragma unroll
  for (int it = 0; it < 4; ++it) {
    int f = (it * 256 + tid) * 4;
    int i = f >> 6, s = f & 63;
    *reinterpret_cast<float4*>(&Ol[i * 68 + s]) =
        *reinterpret_cast<const float4*>(&on[((size_t)(br * HW + hw0 + i) * 8 + b) * 64 + s]);
  }
  __syncthreads();
  float4 orow[16];
#pragma unroll
  for (int qd = 0; qd < 16; ++qd)
    orow[qd] = *reinterpret_cast<const float4*>(&Ol[lane * 68 + qd * 4]);
  float acc[16];
#pragma unroll
  for (int j = 0; j < 16; ++j) {
    const float* wrow = &wl[(size_t)(c0 + cq * 16 + j) * 64];
    float a = 0.f;
#pragma unroll
    for (int qd = 0; qd < 16; ++qd) {
      float4 wv = *reinterpret_cast<const float4*>(&wrow[qd * 4]);
      a = fmaf(orow[qd].w, wv.w, fmaf(orow[qd].z, wv.z, fmaf(orow[qd].y, wv.y, fmaf(orow[qd].x, wv.x, a))));
    }
    acc[j] = a;
  }
#pragma unroll
  for (int j = 0; j < 16; ++j)
    out[((size_t)brb * 512 + c0 + cq * 16 + j) * HW + hw0 + lane] = acc[j];
}

extern "C" void kernel_launch(void* const* d_in, const int* in_sizes, int n_in,
                              void* d_out, int out_size, void* d_ws, size_t ws_size,
                              hipStream_t stream) {
  const float* q  = (const float*)d_in[0];
  const float* k  = (const float*)d_in[1];
  const float* v  = (const float*)d_in[2];
  const float* Wq = (const float*)d_in[3];
  const float* Wk = (const float*)d_in[4];
  const float* Wv = (const float*)d_in[5];
  const float* Wl = (const float*)d_in[6];
  float* out = (float*)d_out;

  float* ap = (float*)d_ws;                         // 3*HW*B*S floats = 25.2 MB
  float* rD = ap + (size_t)3 * HW * 512;            // 3*64*64*64 floats = 3.1 MB
  float* on = rD + (size_t)3 * 64 * 64 * 64;        // 3*HW*B*S floats = 25.2 MB
  ushort* whi  = (ushort*)rD;                       // 192 KB, consumed before denom overwrites rD
  ushort* wmid = whi + (size_t)3 * SDIM * CCH;
  ushort* wlo  = wmid + (size_t)3 * SDIM * CCH;

  prep_kernel<<<dim3(32, 3), 256, 0, stream>>>(Wq, Wk, Wv, whi, wmid, wlo);
  proj_mfma_kernel<<<dim3(32, 8, 3), 256, 0, stream>>>(q, k, v, whi, wmid, wlo, ap);
  denom_kernel<<<dim3(64, 3), 512, 0, stream>>>(ap, rD);
  attn_kernel<<<dim3(8, 64, 3), 256, 0, stream>>>(ap, rD, on);
  out_kernel<<<dim3(8, 64, 24), 256, 0, stream>>>(on, Wl, out);
}

// Round 10
// 318.987 us; speedup vs baseline: 1.1735x; 1.0296x over previous
//
#include <hip/hip_runtime.h>
#include <hip/hip_bf16.h>

#define HW 4096
#define CCH 512
#define SDIM 64
#define BDIM 8

typedef __attribute__((ext_vector_type(8))) short short8;
typedef __attribute__((ext_vector_type(4))) float f32x4;

static __device__ __forceinline__ ushort f2bf(float f) {
  __hip_bfloat16 h = __float2bfloat16(f);  // RNE
  return *reinterpret_cast<ushort*>(&h);
}
static __device__ __forceinline__ float bf2f(ushort u) {
  union { unsigned int u32; float f; } c;
  c.u32 = ((unsigned int)u) << 16;
  return c.f;
}

// async global->LDS DMA: each lane contributes 16B; LDS dest = uniform base + lane*16
static __device__ __forceinline__ void gll16(const float* g, float* lds_base) {
  __builtin_amdgcn_global_load_lds(
      (const __attribute__((address_space(1))) unsigned int*)g,
      (__attribute__((address_space(3))) unsigned int*)lds_base, 16, 0, 0);
}

// K0: split the three projection weights into bf16 hi/mid/lo triples [br][s][c]
__global__ __launch_bounds__(256) void prep_kernel(const float* __restrict__ Wq,
                                                   const float* __restrict__ Wk,
                                                   const float* __restrict__ Wv,
                                                   ushort* __restrict__ whi,
                                                   ushort* __restrict__ wmid,
                                                   ushort* __restrict__ wlo) {
  const float* W = blockIdx.y == 0 ? Wq : (blockIdx.y == 1 ? Wk : Wv);
  const int idx = blockIdx.x * 1024 + threadIdx.x * 4;
  float4 f = *reinterpret_cast<const float4*>(&W[idx]);
  ushort4 h, m, l;
  float r, r2;
  h.x = f2bf(f.x); r = f.x - bf2f(h.x); m.x = f2bf(r); r2 = r - bf2f(m.x); l.x = f2bf(r2);
  h.y = f2bf(f.y); r = f.y - bf2f(h.y); m.y = f2bf(r); r2 = r - bf2f(m.y); l.y = f2bf(r2);
  h.z = f2bf(f.z); r = f.z - bf2f(h.z); m.z = f2bf(r); r2 = r - bf2f(m.z); l.z = f2bf(r2);
  h.w = f2bf(f.w); r = f.w - bf2f(h.w); m.w = f2bf(r); r2 = r - bf2f(m.w); l.w = f2bf(r2);
  const size_t o = (size_t)blockIdx.y * (SDIM * CCH) + idx;
  *reinterpret_cast<ushort4*>(&whi[o])  = h;
  *reinterpret_cast<ushort4*>(&wmid[o]) = m;
  *reinterpret_cast<ushort4*>(&wlo[o])  = l;
}

// K1: 3-way-split bf16 MFMA projection, Ootomo two-accumulator, M=128.
//   Per-wave PRIVATE LDS double-buffer filled via async global_load_lds;
//   counted vmcnt(8) keeps next chunk's DMA in flight; NO __syncthreads.
//   ap[br][hw][b][s] = sum_c x_br[b][c][hw] * w_br[s][c]
__global__ __launch_bounds__(256, 2) void proj_mfma_kernel(const float* __restrict__ q,
                                                           const float* __restrict__ k,
                                                           const float* __restrict__ v,
                                                           const ushort* __restrict__ whi,
                                                           const ushort* __restrict__ wmid,
                                                           const ushort* __restrict__ wlo,
                                                           float* __restrict__ ap) {
  __shared__ float Xs[2][4][64 * 32];  // [buf][wave][c_local*32 + hw'] = 64 KB
  const int mt = blockIdx.x;   // hw tile of 128
  const int b = blockIdx.y;
  const int br = blockIdx.z;
  const float* x = br == 0 ? q : (br == 1 ? k : v);
  const ushort* wh = whi + (size_t)br * SDIM * CCH;
  const ushort* wm = wmid + (size_t)br * SDIM * CCH;
  const ushort* wl = wlo + (size_t)br * SDIM * CCH;
  float* apo = ap + (size_t)br * HW * 512;
  const int hw0 = mt * 128;
  const int tid = threadIdx.x;
  const int l = tid & 63;
  const int wid = tid >> 6;
  const int wstrip = wid * 32;         // wave's 32-column hw strip
  const int row16 = l & 15;
  const int kgrp = l >> 4;
  // staging: lane covers c_local = j*8 + (l>>3), hw' = (l&7)*4 .. +3  (16B contiguous)
  const float* xsrc = x + (size_t)b * CCH * HW + hw0 + wstrip + (l & 7) * 4;
  const int csub = l >> 3;

  f32x4 acc_hi[2][4] = {};
  f32x4 acc_co[2][4] = {};

#define STAGE(BUF, C0)                                                        \
  do {                                                                        \
    float* ldsb = &Xs[BUF][wid][0];                                           \
    _Pragma("unroll") for (int j = 0; j < 8; ++j)                             \
      gll16(xsrc + (size_t)((C0) + j * 8 + csub) * HW, ldsb + j * 256);       \
  } while (0)

#define COMPUTE(BUF, C0)                                                                           \
  do {                                                                                             \
    const float* lw = &Xs[BUF][wid][0];                                                            \
    _Pragma("unroll") for (int ks = 0; ks < 2; ++ks) {                                             \
      short8 bh[4], bm[4], bl[4];                                                                  \
      _Pragma("unroll") for (int nf = 0; nf < 4; ++nf) {                                           \
        const size_t off = (size_t)(nf * 16 + row16) * CCH + (C0) + ks * 32 + kgrp * 8;            \
        bh[nf] = *reinterpret_cast<const short8*>(&wh[off]);                                       \
        bm[nf] = *reinterpret_cast<const short8*>(&wm[off]);                                       \
        bl[nf] = *reinterpret_cast<const short8*>(&wl[off]);                                       \
      }                                                                                            \
      _Pragma("unroll") for (int mf = 0; mf < 2; ++mf) {                                           \
        ushort th[8], tm[8], tl[8];                                                                \
        _Pragma("unroll") for (int i = 0; i < 8; ++i) {                                            \
          const float f = lw[(ks * 32 + kgrp * 8 + i) * 32 + mf * 16 + row16];                     \
          const ushort h = f2bf(f);                                                                \
          const float r = f - bf2f(h);                                                             \
          const ushort mv = f2bf(r);                                                               \
          const float r2 = r - bf2f(mv);                                                           \
          th[i] = h; tm[i] = mv; tl[i] = f2bf(r2);                                                 \
        }                                                                                          \
        const short8 ah = *reinterpret_cast<const short8*>(th);                                    \
        const short8 am = *reinterpret_cast<const short8*>(tm);                                    \
        const short8 al = *reinterpret_cast<const short8*>(tl);                                    \
        _Pragma("unroll") for (int nf = 0; nf < 4; ++nf) {                                         \
          acc_hi[mf][nf] = __builtin_amdgcn_mfma_f32_16x16x32_bf16(ah, bh[nf], acc_hi[mf][nf], 0, 0, 0); \
          acc_co[mf][nf] = __builtin_amdgcn_mfma_f32_16x16x32_bf16(ah, bm[nf], acc_co[mf][nf], 0, 0, 0); \
          acc_co[mf][nf] = __builtin_amdgcn_mfma_f32_16x16x32_bf16(am, bh[nf], acc_co[mf][nf], 0, 0, 0); \
          acc_co[mf][nf] = __builtin_amdgcn_mfma_f32_16x16x32_bf16(am, bm[nf], acc_co[mf][nf], 0, 0, 0); \
          acc_co[mf][nf] = __builtin_amdgcn_mfma_f32_16x16x32_bf16(ah, bl[nf], acc_co[mf][nf], 0, 0, 0); \
          acc_co[mf][nf] = __builtin_amdgcn_mfma_f32_16x16x32_bf16(al, bh[nf], acc_co[mf][nf], 0, 0, 0); \
          acc_co[mf][nf] = __builtin_amdgcn_mfma_f32_16x16x32_bf16(am, bl[nf], acc_co[mf][nf], 0, 0, 0); \
          acc_co[mf][nf] = __builtin_amdgcn_mfma_f32_16x16x32_bf16(al, bm[nf], acc_co[mf][nf], 0, 0, 0); \
        }                                                                                          \
      }                                                                                            \
    }                                                                                              \
  } while (0)

  STAGE(0, 0);
#pragma unroll
  for (int cc = 0; cc < 8; ++cc) {
    if (cc < 7) STAGE((cc + 1) & 1, (cc + 1) * 64);
    __builtin_amdgcn_sched_barrier(0);
    if (cc < 7) {
      asm volatile("s_waitcnt vmcnt(8)" ::: "memory");   // chunk cc's DMAs done; cc+1 in flight
    } else {
      asm volatile("s_waitcnt vmcnt(0)" ::: "memory");
    }
    __builtin_amdgcn_sched_barrier(0);
    COMPUTE(cc & 1, cc * 64);
  }
#undef STAGE
#undef COMPUTE

#pragma unroll
  for (int mf = 0; mf < 2; ++mf)
#pragma unroll
    for (int nf = 0; nf < 4; ++nf)
#pragma unroll
      for (int r = 0; r < 4; ++r) {
        const int m = hw0 + wstrip + mf * 16 + kgrp * 4 + r;
        apo[(size_t)m * 512 + b * 64 + nf * 16 + row16] = acc_hi[mf][nf][r] + acc_co[mf][nf][r];
      }
}

// K2: rD[br][h][s][t] = 1 / sum_w exp( sum_b A[h,w,b,s]*B[h,w,b,t] )
__global__ __launch_bounds__(512) void denom_kernel(const float* __restrict__ ap,
                                                    float* __restrict__ rD) {
  __shared__ float As[8 * 64];
  __shared__ float Bs[8 * 64];
  const int h = blockIdx.x, br = blockIdx.y;
  const float* A  = ap + ((size_t)br * HW + (size_t)h * 64) * (BDIM * SDIM);
  const float* Bp = ap + ((size_t)((br + 1) % 3) * HW + (size_t)h * 64) * (BDIM * SDIM);
  const int tid = threadIdx.x;
  const int t = tid & 63;
  const int sb = (tid >> 6) * 8;
  float D[8] = {};
  for (int w = 0; w < 64; ++w) {
    __syncthreads();
    As[tid] = A[w * (BDIM * SDIM) + tid];
    Bs[tid] = Bp[w * (BDIM * SDIM) + tid];
    __syncthreads();
    float bv[8];
#pragma unroll
    for (int b = 0; b < 8; ++b) bv[b] = Bs[b * 64 + t];
#pragma unroll
    for (int j = 0; j < 8; ++j) {
      float m = 0.f;
#pragma unroll
      for (int b = 0; b < 8; ++b) m = fmaf(As[b * 64 + sb + j], bv[b], m);
      D[j] += __expf(m);
    }
  }
#pragma unroll
  for (int j = 0; j < 8; ++j)
    rD[((size_t)(br * 64 + h) * 64 + sb + j) * 64 + t] = 1.0f / D[j];
}

// K3: on[br][hw][b][s] = o[s][b]/N[b], o = mtilde * C^T
__global__ __launch_bounds__(256) void attn_kernel(const float* __restrict__ ap,
                                                   const float* __restrict__ rD,
                                                   float* __restrict__ on) {
  __shared__ float As[8 * 64], Bs[8 * 64], Cs[8 * 64];
  __shared__ float Ms[64 * 68];  // [s][t] padded
  const int wc = blockIdx.x, h = blockIdx.y, br = blockIdx.z;
  const float* A  = ap + ((size_t)br * HW + h * 64) * 512;
  const float* Bp = ap + ((size_t)((br + 1) % 3) * HW + h * 64) * 512;
  const float* Cp = ap + ((size_t)((br + 2) % 3) * HW + h * 64) * 512;
  const float* rDp = rD + (size_t)(br * 64 + h) * 4096;  // [s][t]
  const int tid = threadIdx.x;
  for (int w = wc * 8; w < wc * 8 + 8; ++w) {
    __syncthreads();
#pragma unroll
    for (int it = 0; it < 2; ++it) {
      int idx = it * 256 + tid;
      As[idx] = A[w * 512 + idx];
      Bs[idx] = Bp[w * 512 + idx];
      Cs[idx] = Cp[w * 512 + idx];
    }
    __syncthreads();
    {
      const int t = tid & 63, sg = tid >> 6;
      float bv[8];
#pragma unroll
      for (int b = 0; b < 8; ++b) bv[b] = Bs[b * 64 + t];
#pragma unroll
      for (int j = 0; j < 16; ++j) {
        int s = sg * 16 + j;
        float m = 0.f;
#pragma unroll
        for (int b = 0; b < 8; ++b) m = fmaf(As[b * 64 + s], bv[b], m);
        Ms[s * 68 + t] = __expf(m) * rDp[s * 64 + t];
      }
    }
    __syncthreads();
    const int s2 = tid & 63, bq = tid >> 6;
    float o0 = 0.f, o1 = 0.f;
#pragma unroll
    for (int tt = 0; tt < 64; tt += 4) {
      float4 mv = *reinterpret_cast<const float4*>(&Ms[s2 * 68 + tt]);
      float4 c0 = *reinterpret_cast<const float4*>(&Cs[bq * 64 + tt]);
      float4 c1 = *reinterpret_cast<const float4*>(&Cs[(bq + 4) * 64 + tt]);
      o0 = fmaf(mv.w, c0.w, fmaf(mv.z, c0.z, fmaf(mv.y, c0.y, fmaf(mv.x, c0.x, o0))));
      o1 = fmaf(mv.w, c1.w, fmaf(mv.z, c1.z, fmaf(mv.y, c1.y, fmaf(mv.x, c1.x, o1))));
    }
    float n0 = o0, n1 = o1;
#pragma unroll
    for (int off = 32; off > 0; off >>= 1) {
      n0 += __shfl_xor(n0, off);
      n1 += __shfl_xor(n1, off);
    }
    const float r0 = 1.0f / n0, r1 = 1.0f / n1;
    const size_t ob = ((size_t)br * HW + h * 64 + w) * 512;
    on[ob + (size_t)bq * 64 + s2] = o0 * r0;
    on[ob + (size_t)(bq + 4) * 64 + s2] = o1 * r1;
  }
}

// K4: out[brb][c][hw] = sum_s on[br][hw][b][s] * wl[c][s]
__global__ __launch_bounds__(256) void out_kernel(const float* __restrict__ on,
                                                  const float* __restrict__ wl,
                                                  float* __restrict__ out) {
  __shared__ float Ol[64 * 68];  // [hw][s] padded
  const int c0 = blockIdx.x * 64;
  const int hw0 = blockIdx.y * 64;
  const int brb = blockIdx.z;
  const int br = brb >> 3, b = brb & 7;
  const int tid = threadIdx.x;
  const int lane = tid & 63;
  const int cq = __builtin_amdgcn_readfirstlane(tid >> 6);
#pragma unroll
  for (int it = 0; it < 4; ++it) {
    int f = (it * 256 + tid) * 4;
    int i = f >> 6, s = f & 63;
    *reinterpret_cast<float4*>(&Ol[i * 68 + s]) =
        *reinterpret_cast<const float4*>(&on[((size_t)(br * HW + hw0 + i) * 8 + b) * 64 + s]);
  }
  __syncthreads();
  float4 orow[16];
#pragma unroll
  for (int qd = 0; qd < 16; ++qd)
    orow[qd] = *reinterpret_cast<const float4*>(&Ol[lane * 68 + qd * 4]);
  float acc[16];
#pragma unroll
  for (int j = 0; j < 16; ++j) {
    const float* wrow = &wl[(size_t)(c0 + cq * 16 + j) * 64];
    float a = 0.f;
#pragma unroll
    for (int qd = 0; qd < 16; ++qd) {
      float4 wv = *reinterpret_cast<const float4*>(&wrow[qd * 4]);
      a = fmaf(orow[qd].w, wv.w, fmaf(orow[qd].z, wv.z, fmaf(orow[qd].y, wv.y, fmaf(orow[qd].x, wv.x, a))));
    }
    acc[j] = a;
  }
#pragma unroll
  for (int j = 0; j < 16; ++j)
    out[((size_t)brb * 512 + c0 + cq * 16 + j) * HW + hw0 + lane] = acc[j];
}

extern "C" void kernel_launch(void* const* d_in, const int* in_sizes, int n_in,
                              void* d_out, int out_size, void* d_ws, size_t ws_size,
                              hipStream_t stream) {
  const float* q  = (const float*)d_in[0];
  const float* k  = (const float*)d_in[1];
  const float* v  = (const float*)d_in[2];
  const float* Wq = (const float*)d_in[3];
  const float* Wk = (const float*)d_in[4];
  const float* Wv = (const float*)d_in[5];
  const float* Wl = (const float*)d_in[6];
  float* out = (float*)d_out;

  float* ap = (float*)d_ws;                         // 3*HW*B*S floats = 25.2 MB
  float* rD = ap + (size_t)3 * HW * 512;            // 3*64*64*64 floats = 3.1 MB
  float* on = rD + (size_t)3 * 64 * 64 * 64;        // 3*HW*B*S floats = 25.2 MB
  ushort* whi  = (ushort*)rD;                       // 192 KB, consumed before denom overwrites rD
  ushort* wmid = whi + (size_t)3 * SDIM * CCH;
  ushort* wlo  = wmid + (size_t)3 * SDIM * CCH;

  prep_kernel<<<dim3(32, 3), 256, 0, stream>>>(Wq, Wk, Wv, whi, wmid, wlo);
  proj_mfma_kernel<<<dim3(32, 8, 3), 256, 0, stream>>>(q, k, v, whi, wmid, wlo, ap);
  denom_kernel<<<dim3(64, 3), 512, 0, stream>>>(ap, rD);
  attn_kernel<<<dim3(8, 64, 3), 256, 0, stream>>>(ap, rD, on);
  out_kernel<<<dim3(8, 64, 24), 256, 0, stream>>>(on, Wl, out);
}

// Round 11
// 283.045 us; speedup vs baseline: 1.3226x; 1.1270x over previous
//
#include <hip/hip_runtime.h>
#include <hip/hip_bf16.h>

#define HW 4096
#define CCH 512
#define SDIM 64
#define BDIM 8

typedef __attribute__((ext_vector_type(8))) short short8;
typedef __attribute__((ext_vector_type(4))) float f32x4;

static __device__ __forceinline__ ushort f2bf(float f) {
  __hip_bfloat16 h = __float2bfloat16(f);  // RNE
  return *reinterpret_cast<ushort*>(&h);
}
static __device__ __forceinline__ float bf2f(ushort u) {
  union { unsigned int u32; float f; } c;
  c.u32 = ((unsigned int)u) << 16;
  return c.f;
}

// async global->LDS DMA: each lane contributes 16B; LDS dest = uniform base + lane*16
static __device__ __forceinline__ void gll16(const float* g, float* lds_base) {
  __builtin_amdgcn_global_load_lds(
      (const __attribute__((address_space(1))) unsigned int*)g,
      (__attribute__((address_space(3))) unsigned int*)lds_base, 16, 0, 0);
}

// K0: split the three projection weights into bf16 hi/mid/lo triples [br][s][c]
__global__ __launch_bounds__(256) void prep_kernel(const float* __restrict__ Wq,
                                                   const float* __restrict__ Wk,
                                                   const float* __restrict__ Wv,
                                                   ushort* __restrict__ whi,
                                                   ushort* __restrict__ wmid,
                                                   ushort* __restrict__ wlo) {
  const float* W = blockIdx.y == 0 ? Wq : (blockIdx.y == 1 ? Wk : Wv);
  const int idx = blockIdx.x * 1024 + threadIdx.x * 4;
  float4 f = *reinterpret_cast<const float4*>(&W[idx]);
  ushort4 h, m, l;
  float r, r2;
  h.x = f2bf(f.x); r = f.x - bf2f(h.x); m.x = f2bf(r); r2 = r - bf2f(m.x); l.x = f2bf(r2);
  h.y = f2bf(f.y); r = f.y - bf2f(h.y); m.y = f2bf(r); r2 = r - bf2f(m.y); l.y = f2bf(r2);
  h.z = f2bf(f.z); r = f.z - bf2f(h.z); m.z = f2bf(r); r2 = r - bf2f(m.z); l.z = f2bf(r2);
  h.w = f2bf(f.w); r = f.w - bf2f(h.w); m.w = f2bf(r); r2 = r - bf2f(m.w); l.w = f2bf(r2);
  const size_t o = (size_t)blockIdx.y * (SDIM * CCH) + idx;
  *reinterpret_cast<ushort4*>(&whi[o])  = h;
  *reinterpret_cast<ushort4*>(&wmid[o]) = m;
  *reinterpret_cast<ushort4*>(&wlo[o])  = l;
}

// K1: 3-way-split bf16 MFMA projection (unchanged from round 10)
__global__ __launch_bounds__(256, 2) void proj_mfma_kernel(const float* __restrict__ q,
                                                           const float* __restrict__ k,
                                                           const float* __restrict__ v,
                                                           const ushort* __restrict__ whi,
                                                           const ushort* __restrict__ wmid,
                                                           const ushort* __restrict__ wlo,
                                                           float* __restrict__ ap) {
  __shared__ float Xs[2][4][64 * 32];  // [buf][wave][c_local*32 + hw'] = 64 KB
  const int mt = blockIdx.x;   // hw tile of 128
  const int b = blockIdx.y;
  const int br = blockIdx.z;
  const float* x = br == 0 ? q : (br == 1 ? k : v);
  const ushort* wh = whi + (size_t)br * SDIM * CCH;
  const ushort* wm = wmid + (size_t)br * SDIM * CCH;
  const ushort* wl = wlo + (size_t)br * SDIM * CCH;
  float* apo = ap + (size_t)br * HW * 512;
  const int hw0 = mt * 128;
  const int tid = threadIdx.x;
  const int l = tid & 63;
  const int wid = tid >> 6;
  const int wstrip = wid * 32;         // wave's 32-column hw strip
  const int row16 = l & 15;
  const int kgrp = l >> 4;
  const float* xsrc = x + (size_t)b * CCH * HW + hw0 + wstrip + (l & 7) * 4;
  const int csub = l >> 3;

  f32x4 acc_hi[2][4] = {};
  f32x4 acc_co[2][4] = {};

#define STAGE(BUF, C0)                                                        \
  do {                                                                        \
    float* ldsb = &Xs[BUF][wid][0];                                           \
    _Pragma("unroll") for (int j = 0; j < 8; ++j)                             \
      gll16(xsrc + (size_t)((C0) + j * 8 + csub) * HW, ldsb + j * 256);       \
  } while (0)

#define COMPUTE(BUF, C0)                                                                           \
  do {                                                                                             \
    const float* lw = &Xs[BUF][wid][0];                                                            \
    _Pragma("unroll") for (int ks = 0; ks < 2; ++ks) {                                             \
      short8 bh[4], bm[4], bl[4];                                                                  \
      _Pragma("unroll") for (int nf = 0; nf < 4; ++nf) {                                           \
        const size_t off = (size_t)(nf * 16 + row16) * CCH + (C0) + ks * 32 + kgrp * 8;            \
        bh[nf] = *reinterpret_cast<const short8*>(&wh[off]);                                       \
        bm[nf] = *reinterpret_cast<const short8*>(&wm[off]);                                       \
        bl[nf] = *reinterpret_cast<const short8*>(&wl[off]);                                       \
      }                                                                                            \
      _Pragma("unroll") for (int mf = 0; mf < 2; ++mf) {                                           \
        ushort th[8], tm[8], tl[8];                                                                \
        _Pragma("unroll") for (int i = 0; i < 8; ++i) {                                            \
          const float f = lw[(ks * 32 + kgrp * 8 + i) * 32 + mf * 16 + row16];                     \
          const ushort h = f2bf(f);                                                                \
          const float r = f - bf2f(h);                                                             \
          const ushort mv = f2bf(r);                                                               \
          const float r2 = r - bf2f(mv);                                                           \
          th[i] = h; tm[i] = mv; tl[i] = f2bf(r2);                                                 \
        }                                                                                          \
        const short8 ah = *reinterpret_cast<const short8*>(th);                                    \
        const short8 am = *reinterpret_cast<const short8*>(tm);                                    \
        const short8 al = *reinterpret_cast<const short8*>(tl);                                    \
        _Pragma("unroll") for (int nf = 0; nf < 4; ++nf) {                                         \
          acc_hi[mf][nf] = __builtin_amdgcn_mfma_f32_16x16x32_bf16(ah, bh[nf], acc_hi[mf][nf], 0, 0, 0); \
          acc_co[mf][nf] = __builtin_amdgcn_mfma_f32_16x16x32_bf16(ah, bm[nf], acc_co[mf][nf], 0, 0, 0); \
          acc_co[mf][nf] = __builtin_amdgcn_mfma_f32_16x16x32_bf16(am, bh[nf], acc_co[mf][nf], 0, 0, 0); \
          acc_co[mf][nf] = __builtin_amdgcn_mfma_f32_16x16x32_bf16(am, bm[nf], acc_co[mf][nf], 0, 0, 0); \
          acc_co[mf][nf] = __builtin_amdgcn_mfma_f32_16x16x32_bf16(ah, bl[nf], acc_co[mf][nf], 0, 0, 0); \
          acc_co[mf][nf] = __builtin_amdgcn_mfma_f32_16x16x32_bf16(al, bh[nf], acc_co[mf][nf], 0, 0, 0); \
          acc_co[mf][nf] = __builtin_amdgcn_mfma_f32_16x16x32_bf16(am, bl[nf], acc_co[mf][nf], 0, 0, 0); \
          acc_co[mf][nf] = __builtin_amdgcn_mfma_f32_16x16x32_bf16(al, bm[nf], acc_co[mf][nf], 0, 0, 0); \
        }                                                                                          \
      }                                                                                            \
    }                                                                                              \
  } while (0)

  STAGE(0, 0);
#pragma unroll
  for (int cc = 0; cc < 8; ++cc) {
    if (cc < 7) STAGE((cc + 1) & 1, (cc + 1) * 64);
    __builtin_amdgcn_sched_barrier(0);
    if (cc < 7) {
      asm volatile("s_waitcnt vmcnt(8)" ::: "memory");
    } else {
      asm volatile("s_waitcnt vmcnt(0)" ::: "memory");
    }
    __builtin_amdgcn_sched_barrier(0);
    COMPUTE(cc & 1, cc * 64);
  }
#undef STAGE
#undef COMPUTE

#pragma unroll
  for (int mf = 0; mf < 2; ++mf)
#pragma unroll
    for (int nf = 0; nf < 4; ++nf)
#pragma unroll
      for (int r = 0; r < 4; ++r) {
        const int m = hw0 + wstrip + mf * 16 + kgrp * 4 + r;
        apo[(size_t)m * 512 + b * 64 + nf * 16 + row16] = acc_hi[mf][nf][r] + acc_co[mf][nf][r];
      }
}

// K2: rD[br][h][s][t] = 1 / sum_w exp( sum_b A[h,w,b,s]*B[h,w,b,t] )
//   s split across 4 blocks (grid 768 = 3/CU); same FMA order -> bit-identical rD
__global__ __launch_bounds__(512) void denom_kernel(const float* __restrict__ ap,
                                                    float* __restrict__ rD) {
  __shared__ float As[8 * 16];   // [b][s_local]
  __shared__ float Bs[8 * 64];   // [b][t]
  const int h = blockIdx.x, br = blockIdx.y, sq = blockIdx.z;
  const float* A  = ap + ((size_t)br * HW + (size_t)h * 64) * (BDIM * SDIM);
  const float* Bp = ap + ((size_t)((br + 1) % 3) * HW + (size_t)h * 64) * (BDIM * SDIM);
  const int tid = threadIdx.x;
  const int t = tid & 63;
  const int sg = tid >> 6;  // 0..7, each covers 2 s
  float D[2] = {};
  for (int w = 0; w < 64; ++w) {
    __syncthreads();
    if (tid < 128) As[tid] = A[w * 512 + (tid >> 4) * 64 + sq * 16 + (tid & 15)];
    Bs[tid] = Bp[w * 512 + tid];
    __syncthreads();
    float bv[8];
#pragma unroll
    for (int b = 0; b < 8; ++b) bv[b] = Bs[b * 64 + t];
#pragma unroll
    for (int j = 0; j < 2; ++j) {
      const int sl = sg * 2 + j;
      float m = 0.f;
#pragma unroll
      for (int b = 0; b < 8; ++b) m = fmaf(As[b * 16 + sl], bv[b], m);
      D[j] += __expf(m);
    }
  }
#pragma unroll
  for (int j = 0; j < 2; ++j)
    rD[((size_t)(br * 64 + h) * 64 + sq * 16 + sg * 2 + j) * 64 + t] = 1.0f / D[j];
}

// K3: on[br][hw][b][s] = o[s][b]/N[b], o = mtilde * C^T  (unchanged)
__global__ __launch_bounds__(256) void attn_kernel(const float* __restrict__ ap,
                                                   const float* __restrict__ rD,
                                                   float* __restrict__ on) {
  __shared__ float As[8 * 64], Bs[8 * 64], Cs[8 * 64];
  __shared__ float Ms[64 * 68];  // [s][t] padded
  const int wc = blockIdx.x, h = blockIdx.y, br = blockIdx.z;
  const float* A  = ap + ((size_t)br * HW + h * 64) * 512;
  const float* Bp = ap + ((size_t)((br + 1) % 3) * HW + h * 64) * 512;
  const float* Cp = ap + ((size_t)((br + 2) % 3) * HW + h * 64) * 512;
  const float* rDp = rD + (size_t)(br * 64 + h) * 4096;  // [s][t]
  const int tid = threadIdx.x;
  for (int w = wc * 8; w < wc * 8 + 8; ++w) {
    __syncthreads();
#pragma unroll
    for (int it = 0; it < 2; ++it) {
      int idx = it * 256 + tid;
      As[idx] = A[w * 512 + idx];
      Bs[idx] = Bp[w * 512 + idx];
      Cs[idx] = Cp[w * 512 + idx];
    }
    __syncthreads();
    {
      const int t = tid & 63, sg = tid >> 6;
      float bv[8];
#pragma unroll
      for (int b = 0; b < 8; ++b) bv[b] = Bs[b * 64 + t];
#pragma unroll
      for (int j = 0; j < 16; ++j) {
        int s = sg * 16 + j;
        float m = 0.f;
#pragma unroll
        for (int b = 0; b < 8; ++b) m = fmaf(As[b * 64 + s], bv[b], m);
        Ms[s * 68 + t] = __expf(m) * rDp[s * 64 + t];
      }
    }
    __syncthreads();
    const int s2 = tid & 63, bq = tid >> 6;
    float o0 = 0.f, o1 = 0.f;
#pragma unroll
    for (int tt = 0; tt < 64; tt += 4) {
      float4 mv = *reinterpret_cast<const float4*>(&Ms[s2 * 68 + tt]);
      float4 c0 = *reinterpret_cast<const float4*>(&Cs[bq * 64 + tt]);
      float4 c1 = *reinterpret_cast<const float4*>(&Cs[(bq + 4) * 64 + tt]);
      o0 = fmaf(mv.w, c0.w, fmaf(mv.z, c0.z, fmaf(mv.y, c0.y, fmaf(mv.x, c0.x, o0))));
      o1 = fmaf(mv.w, c1.w, fmaf(mv.z, c1.z, fmaf(mv.y, c1.y, fmaf(mv.x, c1.x, o1))));
    }
    float n0 = o0, n1 = o1;
#pragma unroll
    for (int off = 32; off > 0; off >>= 1) {
      n0 += __shfl_xor(n0, off);
      n1 += __shfl_xor(n1, off);
    }
    const float r0 = 1.0f / n0, r1 = 1.0f / n1;
    const size_t ob = ((size_t)br * HW + h * 64 + w) * 512;
    on[ob + (size_t)bq * 64 + s2] = o0 * r0;
    on[ob + (size_t)(bq + 4) * 64 + s2] = o1 * r1;
  }
}

// K4: out[brb][c][hw] = sum_s on[br][hw][b][s] * wl[c][s]
//   MFMA role-swap: M = c (512), N = hw (128-tile), K = s (64).
//   A = Wl rows (contiguous s), B = on rows (contiguous s, LDS-staged once),
//   D stores 16-lane-consecutive hw. Both operands hi/lo split, 3 terms.
__global__ __launch_bounds__(256) void out_kernel(const float* __restrict__ on,
                                                  const float* __restrict__ wl,
                                                  float* __restrict__ out) {
  __shared__ float Os[128 * 68];  // [hw_local][s] pad 68
  const int hwt = blockIdx.x;     // 32 tiles of 128 hw
  const int brb = blockIdx.y;     // 0..23
  const int br = brb >> 3, b = brb & 7;
  const int hw0 = hwt * 128;
  const int tid = threadIdx.x;
  const int l = tid & 63;
  const int wv = tid >> 6;        // wave 0..3 -> hw strip of 32
  const int l15 = l & 15;
  const int kgrp = l >> 4;

  // stage on[hw0..+128][0..64] fp32 -> LDS (coalesced 64B per 16 threads)
  {
    const int row = tid >> 4;
    const int s4 = (tid & 15) * 4;
#pragma unroll
    for (int it = 0; it < 8; ++it) {
      const int r = row + it * 16;
      *reinterpret_cast<float4*>(&Os[r * 68 + s4]) =
          *reinterpret_cast<const float4*>(&on[((size_t)(br * HW + hw0 + r) * 8 + b) * 64 + s4]);
    }
  }
  __syncthreads();

  // B fragments (on): hi/lo for nf=0..1, ks=0..1; reused across all 32 c-frags
  short8 onh[2][2], onl[2][2];
#pragma unroll
  for (int nf = 0; nf < 2; ++nf)
#pragma unroll
    for (int ks = 0; ks < 2; ++ks) {
      const int row = wv * 32 + nf * 16 + l15;
      const float* p = &Os[row * 68 + ks * 32 + kgrp * 8];
      ushort th[8], tl[8];
#pragma unroll
      for (int i = 0; i < 8; ++i) {
        const float f = p[i];
        const ushort h = f2bf(f);
        th[i] = h;
        tl[i] = f2bf(f - bf2f(h));
      }
      onh[nf][ks] = *reinterpret_cast<const short8*>(th);
      onl[nf][ks] = *reinterpret_cast<const short8*>(tl);
    }

  // c loop: A = Wl[c][s] (L2-hot), split hi/lo in regs; single fp32 accumulator
  for (int mf = 0; mf < 32; ++mf) {
    f32x4 acc[2] = {};
#pragma unroll
    for (int ks = 0; ks < 2; ++ks) {
      const float* wp = &wl[(size_t)(mf * 16 + l15) * 64 + ks * 32 + kgrp * 8];
      ushort th[8], tl[8];
#pragma unroll
      for (int i = 0; i < 8; ++i) {
        const float f = wp[i];
        const ushort h = f2bf(f);
        th[i] = h;
        tl[i] = f2bf(f - bf2f(h));
      }
      const short8 wh8 = *reinterpret_cast<const short8*>(th);
      const short8 wl8 = *reinterpret_cast<const short8*>(tl);
#pragma unroll
      for (int nf = 0; nf < 2; ++nf) {
        acc[nf] = __builtin_amdgcn_mfma_f32_16x16x32_bf16(wh8, onh[nf][ks], acc[nf], 0, 0, 0);
        acc[nf] = __builtin_amdgcn_mfma_f32_16x16x32_bf16(wh8, onl[nf][ks], acc[nf], 0, 0, 0);
        acc[nf] = __builtin_amdgcn_mfma_f32_16x16x32_bf16(wl8, onh[nf][ks], acc[nf], 0, 0, 0);
      }
    }
#pragma unroll
    for (int nf = 0; nf < 2; ++nf)
#pragma unroll
      for (int r = 0; r < 4; ++r) {
        const int cc = mf * 16 + kgrp * 4 + r;
        out[(size_t)(brb * 512 + cc) * HW + hw0 + wv * 32 + nf * 16 + l15] = acc[nf][r];
      }
  }
}

extern "C" void kernel_launch(void* const* d_in, const int* in_sizes, int n_in,
                              void* d_out, int out_size, void* d_ws, size_t ws_size,
                              hipStream_t stream) {
  const float* q  = (const float*)d_in[0];
  const float* k  = (const float*)d_in[1];
  const float* v  = (const float*)d_in[2];
  const float* Wq = (const float*)d_in[3];
  const float* Wk = (const float*)d_in[4];
  const float* Wv = (const float*)d_in[5];
  const float* Wl = (const float*)d_in[6];
  float* out = (float*)d_out;

  float* ap = (float*)d_ws;                         // 3*HW*B*S floats = 25.2 MB
  float* rD = ap + (size_t)3 * HW * 512;            // 3*64*64*64 floats = 3.1 MB
  float* on = rD + (size_t)3 * 64 * 64 * 64;        // 3*HW*B*S floats = 25.2 MB
  ushort* whi  = (ushort*)rD;                       // 192 KB, consumed before denom overwrites rD
  ushort* wmid = whi + (size_t)3 * SDIM * CCH;
  ushort* wlo  = wmid + (size_t)3 * SDIM * CCH;

  prep_kernel<<<dim3(32, 3), 256, 0, stream>>>(Wq, Wk, Wv, whi, wmid, wlo);
  proj_mfma_kernel<<<dim3(32, 8, 3), 256, 0, stream>>>(q, k, v, whi, wmid, wlo, ap);
  denom_kernel<<<dim3(64, 3, 4), 512, 0, stream>>>(ap, rD);
  attn_kernel<<<dim3(8, 64, 3), 256, 0, stream>>>(ap, rD, on);
  out_kernel<<<dim3(32, 24), 256, 0, stream>>>(on, Wl, out);
}